// Round 2
// baseline (296.920 us; speedup 1.0000x reference)
//
#include <hip/hip_runtime.h>
#include <math.h>

#define NCLS 20
#define IGNORE_IDX 255
#define LOG2E 1.4426950408889634f
#define NBLK 512
#define NTHR 256

typedef float v4f __attribute__((ext_vector_type(4)));
typedef int v4i __attribute__((ext_vector_type(4)));

__device__ int g_cnt;  // zero at module load; last block resets it each launch

__device__ __forceinline__ float wave_reduce(float v) {
#pragma unroll
  for (int off = 32; off > 0; off >>= 1) v += __shfl_xor(v, off, 64);
  return v;
}

__device__ __forceinline__ float neg_log_clamped(float x, bool cond) {
  if (!cond) return 0.0f;
  float xs = fmaxf(x, 1e-38f);
  return fminf(-logf(xs), 100.0f);
}

// ws row layout per block (64 floats): [0..19] sum_p, [20..39] nominator,
// [40..59] ct_count, [60..63] zero pad.
__global__ __launch_bounds__(NTHR) void fused(const float* __restrict__ pred,
                                              const int* __restrict__ target,
                                              float* __restrict__ ws,
                                              float* __restrict__ out, int N) {
  __shared__ float s_acc[3 * NCLS];
  __shared__ float s_fin[64];
  __shared__ int s_last;
  const int tid = threadIdx.x;
  for (int i = tid; i < 3 * NCLS; i += NTHR) s_acc[i] = 0.0f;
  if (tid < 64) s_fin[tid] = 0.0f;
  __syncthreads();

  float acc[NCLS];
#pragma unroll
  for (int c = 0; c < NCLS; ++c) acc[c] = 0.0f;

  const int nq = N >> 2;           // quads of voxels; exact (N % 4 == 0)
  const int tot = NBLK * NTHR;     // 131072 threads; nq/tot = 4 exactly here
  for (int q = blockIdx.x * NTHR + tid; q < nq; q += tot) {
    const int n = q << 2;
    v4f x[NCLS];
#pragma unroll
    for (int c = 0; c < NCLS; ++c)
      x[c] = __builtin_nontemporal_load(
          reinterpret_cast<const v4f*>(pred + (size_t)c * N + n));

    v4f m = x[0];
#pragma unroll
    for (int c = 1; c < NCLS; ++c) {
#pragma unroll
      for (int j = 0; j < 4; ++j) m[j] = fmaxf(m[j], x[c][j]);
    }

    const v4i t4 = *reinterpret_cast<const v4i*>(target + n);

    v4f s = (v4f)(0.0f);
    v4f pt = (v4f)(0.0f);
#pragma unroll
    for (int c = 0; c < NCLS; ++c) {
#pragma unroll
      for (int j = 0; j < 4; ++j) {
        x[c][j] = __builtin_amdgcn_exp2f((x[c][j] - m[j]) * LOG2E);
        s[j] += x[c][j];
        pt[j] = (c == t4[j]) ? x[c][j] : pt[j];
      }
    }

    float w[4];
    bool msk[4];
#pragma unroll
    for (int j = 0; j < 4; ++j) {
      msk[j] = (t4[j] != IGNORE_IDX);
      const float r = __builtin_amdgcn_rcpf(s[j]);
      w[j] = msk[j] ? r : 0.0f;
    }

#pragma unroll
    for (int c = 0; c < NCLS; ++c)
      acc[c] += x[c][0] * w[0] + x[c][1] * w[1] + x[c][2] * w[2] + x[c][3] * w[3];

#pragma unroll
    for (int j = 0; j < 4; ++j) {
      if (msk[j]) {
        atomicAdd(&s_acc[NCLS + t4[j]], pt[j] * w[j]);
        atomicAdd(&s_acc[2 * NCLS + t4[j]], 1.0f);
      }
    }
  }

  // block-reduce sum_p: wave butterfly, lane0 -> LDS
#pragma unroll
  for (int c = 0; c < NCLS; ++c) {
    float v = wave_reduce(acc[c]);
    if ((tid & 63) == 0) atomicAdd(&s_acc[c], v);
  }
  __syncthreads();

  // publish this block's 60 partials (plus zero pad) to its ws row
  if (tid < 64)
    ws[(size_t)blockIdx.x * 64 + tid] = (tid < 3 * NCLS) ? s_acc[tid] : 0.0f;
  __threadfence();  // release our stores to agent scope
  __syncthreads();

  if (tid == 0) {
    int old = __hip_atomic_fetch_add(&g_cnt, 1, __ATOMIC_ACQ_REL,
                                     __HIP_MEMORY_SCOPE_AGENT);
    s_last = (old == (int)gridDim.x - 1);
    if (s_last)
      __hip_atomic_store(&g_cnt, 0, __ATOMIC_RELAXED, __HIP_MEMORY_SCOPE_AGENT);
  }
  __syncthreads();
  if (!s_last) return;

  __threadfence();  // acquire: make all blocks' ws rows visible

  // Column-sum: flat idx = row*64 + col; thread t reads idx ≡ t (mod 256),
  // so col = t & 63 is constant per thread; rows covered exactly once.
  float a = 0.0f;
  const int total = NBLK * 64;
  for (int i = tid; i < total; i += NTHR) a += ws[i];
  atomicAdd(&s_fin[tid & 63], a);  // 4 waves, no intra-wave same-addr conflict
  __syncthreads();

  // wave 0 computes the final scalar
  if (tid < 64) {
    const float cnt = (tid < NCLS) ? s_fin[2 * NCLS + tid] : 0.0f;
    const float n_masked = wave_reduce(cnt);
    float loss = 0.0f, validf = 0.0f;
    if (tid < NCLS) {
      const float sump = s_fin[tid];
      const float nom = s_fin[NCLS + tid];
      const bool valid = cnt > 0.0f;
      const float prec = nom / fmaxf(sump, 1e-38f);
      const float rec = nom / fmaxf(cnt, 1.0f);
      const float negc = n_masked - cnt;
      const float specn = n_masked - sump - cnt + nom;
      const float spec = specn / fmaxf(negc, 1.0f);
      loss = neg_log_clamped(prec, valid && (sump > 0.0f)) +
             neg_log_clamped(rec, valid) +
             neg_log_clamped(spec, valid && (negc > 0.0f));
      validf = valid ? 1.0f : 0.0f;
    }
    loss = wave_reduce(loss);
    validf = wave_reduce(validf);
    if (tid == 0) out[0] = loss / validf;
  }
}

extern "C" void kernel_launch(void* const* d_in, const int* in_sizes, int n_in,
                              void* d_out, int out_size, void* d_ws, size_t ws_size,
                              hipStream_t stream) {
  const float* pred = (const float*)d_in[0];
  const int* target = (const int*)d_in[1];
  const int N = in_sizes[1];  // voxel count; C = in_sizes[0]/N = 20
  fused<<<NBLK, NTHR, 0, stream>>>(pred, target, (float*)d_ws, (float*)d_out, N);
}